// Round 11
// baseline (406.324 us; speedup 1.0000x reference)
//
#include <hip/hip_runtime.h>
#include <cmath>

typedef unsigned short u16;
typedef unsigned int u32;
typedef __attribute__((ext_vector_type(8))) __bf16 bf16x8;
typedef __attribute__((ext_vector_type(8))) u16 u16x8;
typedef __attribute__((ext_vector_type(4))) float f32x4;
typedef __attribute__((ext_vector_type(4))) u16 u16x4;

#define MFMA16(acc, a, b) (acc) = __builtin_amdgcn_mfma_f32_16x16x32_bf16((a), (b), (acc), 0, 0, 0)

__device__ __forceinline__ u16 f2bf(float x) {
  union { float f; u32 u; } c; c.f = x;
  u32 r = (c.u + 0x7FFFu + ((c.u >> 16) & 1u)) >> 16;
  return (u16)r;
}
__device__ __forceinline__ float bf2f(u16 b) {
  union { u32 u; float f; } c; c.u = ((u32)b) << 16;
  return c.f;
}
__device__ __forceinline__ float rowmax16(float v) {
#pragma unroll
  for (int m = 1; m < 16; m <<= 1) v = fmaxf(v, __shfl_xor(v, m));
  return v;
}
__device__ __forceinline__ float rowsum16(float v) {
#pragma unroll
  for (int m = 1; m < 16; m <<= 1) v += __shfl_xor(v, m);
  return v;
}
__device__ __forceinline__ void gload16(const u16* g, u16* l) {
  __builtin_amdgcn_global_load_lds(
      (const __attribute__((address_space(1))) void*)(g),
      (__attribute__((address_space(3))) void*)(l), 16, 0, 0);
}
__device__ __forceinline__ float exp2_asm(float x) {
  float r;
  asm("v_exp_f32 %0, %1\n\ts_nop 0" : "=v"(r) : "v"(x));
  return r;
}
__device__ __forceinline__ u32 cvtpk(float a, float b) {
  u32 r;
  asm("v_cvt_pk_bf16_f32 %0, %1, %2" : "=v"(r) : "v"(a), "v"(b));
  return r;
}
__device__ __forceinline__ u16x8 bc_u(bf16x8 v) { union { bf16x8 b; u16x8 u; } c; c.b = v; return c.u; }
__device__ __forceinline__ bf16x8 bc_b(u16x8 v) { union { u16x8 u; bf16x8 b; } c; c.u = v; return c.b; }
__device__ __forceinline__ bf16x8 pack8(f32x4 a, f32x4 b) {
  union { u32 w[4]; bf16x8 v; } c;
  c.w[0] = cvtpk(a[0], a[1]);
  c.w[1] = cvtpk(a[2], a[3]);
  c.w[2] = cvtpk(b[0], b[1]);
  c.w[3] = cvtpk(b[2], b[3]);
  return c.v;
}
// chain: after swap32 then swap16, a = frag word pair {keys +0,+1}-per-quadrant,
// c = {keys +4,+5} (derivation verified in round 10)
__device__ __forceinline__ void swapchain(u32& a, u32& c) {
  asm("v_permlane32_swap_b32 %0, %1" : "+v"(a), "+v"(c));
  asm("v_permlane16_swap_b32 %0, %1" : "+v"(a), "+v"(c));
}

// ---------------- freqs table --------------------------------------------------
__global__ void freqs_kernel(float* __restrict__ ct, float* __restrict__ st) {
  int idx = blockIdx.x * 256 + threadIdx.x;  // t*32 + i
  int t = idx >> 5, i = idx & 31;
  float inv = 1.0f / powf(10000.0f, (float)i / 32.0f);
  float a = (float)t * inv;
  float sv, cv;
  sincosf(a, &sv, &cv);
  ct[idx] = cv;
  st[idx] = sv;
}

// ---------------- fp32 -> bf16 flat convert (x) --------------------------------
__global__ void cvt_x_kernel(const float* __restrict__ in, u16* __restrict__ out) {
  int idx = (blockIdx.x * 256 + threadIdx.x) * 4;
  f32x4 v = *(const f32x4*)(in + idx);
  u16x4 o;
  o[0] = f2bf(v[0]); o[1] = f2bf(v[1]); o[2] = f2bf(v[2]); o[3] = f2bf(v[3]);
  *(u16x4*)(out + idx) = o;
}

// ---------------- transpose + convert: Wt[n*K+k] = bf16(W[k*N+n]) --------------
__global__ __launch_bounds__(256) void trcvt_kernel(const float* __restrict__ W,
                                                    u16* __restrict__ Wt, int K, int N) {
  __shared__ u16 t_lds[64][65];
  int ntx = N >> 6;
  int kt = (blockIdx.x / ntx) * 64, nt = (blockIdx.x % ntx) * 64;
  int tx = threadIdx.x & 63, ty4 = threadIdx.x >> 6;
#pragma unroll 4
  for (int yy = 0; yy < 16; ++yy) {
    int k = kt + ty4 * 16 + yy;
    t_lds[ty4 * 16 + yy][tx] = f2bf(W[(size_t)k * N + nt + tx]);
  }
  __syncthreads();
#pragma unroll 4
  for (int yy = 0; yy < 16; ++yy) {
    int n = nt + ty4 * 16 + yy;
    Wt[(size_t)n * K + kt + tx] = t_lds[tx][ty4 * 16 + yy];
  }
}

// ---------------- m97-structure bf16 MFMA GEMM + XCD swizzle -------------------
__global__ __launch_bounds__(256) void gemm_bt_kernel(const u16* __restrict__ A,
                                                      const u16* __restrict__ Bt,
                                                      float* __restrict__ C,
                                                      int M, int N, int K) {
  __shared__ __align__(16) u16 As[128 * 64];
  __shared__ __align__(16) u16 Bs[128 * 64];
  const int tid = threadIdx.x;
  const int lane = tid & 63;
  const int w = tid >> 6;
  const int lr = lane & 15;
  const int lg = lane >> 4;
  const int lk8 = lg * 8;
  // XCD-aware bijective swizzle (all our grids have nwg % 8 == 0)
  const int gx = gridDim.x;
  const int nwg = gx * gridDim.y;
  const int flat = blockIdx.y * gx + blockIdx.x;
  const int qq = nwg >> 3;
  const int swz = (flat & 7) * qq + (flat >> 3);
  const int brow = (swz % gx) * 128;
  const int bcol = (swz / gx) * 128;
  const int wr = (w >> 1) * 64;
  const int wc = (w & 1) * 64;

  const f32x4 zero4 = {0.f, 0.f, 0.f, 0.f};
  f32x4 acc[4][4];
#pragma unroll
  for (int m = 0; m < 4; ++m)
#pragma unroll
    for (int n = 0; n < 4; ++n) acc[m][n] = zero4;

  const int srow = tid >> 3;
  const int scol = (tid & 7) * 8;
  const u16* Ab = A + (size_t)(brow + srow) * K + scol;
  const u16* Bb = Bt + (size_t)(bcol + srow) * K + scol;

  for (int k0 = 0; k0 < K; k0 += 64) {
    __syncthreads();
#pragma unroll
    for (int it = 0; it < 4; ++it) {
      gload16(Ab + (size_t)it * 32 * K + k0, &As[tid * 8 + it * 2048]);
      gload16(Bb + (size_t)it * 32 * K + k0, &Bs[tid * 8 + it * 2048]);
    }
    __syncthreads();
#pragma unroll
    for (int kk = 0; kk < 2; ++kk) {
      bf16x8 af[4], bv[4];
#pragma unroll
      for (int m = 0; m < 4; ++m)
        af[m] = *(const bf16x8*)&As[(wr + m * 16 + lr) * 64 + kk * 32 + lk8];
#pragma unroll
      for (int n = 0; n < 4; ++n)
        bv[n] = *(const bf16x8*)&Bs[(wc + n * 16 + lr) * 64 + kk * 32 + lk8];
#pragma unroll
      for (int m = 0; m < 4; ++m)
#pragma unroll
        for (int n = 0; n < 4; ++n) MFMA16(acc[m][n], af[m], bv[n]);
    }
  }
#pragma unroll
  for (int m = 0; m < 4; ++m) {
#pragma unroll
    for (int rr = 0; rr < 4; ++rr) {
      int row = brow + wr + m * 16 + lg * 4 + rr;
#pragma unroll
      for (int n = 0; n < 4; ++n)
        C[(size_t)row * N + bcol + wc + n * 16 + lr] = acc[m][n][rr];
    }
  }
}

// ---------------- RoPE: qkv (T,3072) -> q (H,T,64) pre-scaled by 1/8 ----------
__global__ void rope_q_kernel(const float* __restrict__ qkv, const float* __restrict__ ct,
                              const float* __restrict__ st, u16* __restrict__ qb) {
  int idx = blockIdx.x * 256 + threadIdx.x;  // t*1024 + h*32 + i
  int i = idx & 31, hh = (idx >> 5) & 31, t = idx >> 10;
  float x0 = qkv[(size_t)t * 3072 + hh * 64 + 2 * i];
  float x1 = qkv[(size_t)t * 3072 + hh * 64 + 2 * i + 1];
  float c = ct[t * 32 + i], s = st[t * 32 + i];
  size_t o = ((size_t)hh * 2048 + t) * 64 + 2 * i;
  qb[o] = f2bf((x0 * c - x1 * s) * 0.125f);
  qb[o + 1] = f2bf((x0 * s + x1 * c) * 0.125f);
}
__global__ void rope_k_kernel(const float* __restrict__ qkv, const float* __restrict__ ct,
                              const float* __restrict__ st, u16* __restrict__ kb) {
  int idx = blockIdx.x * 256 + threadIdx.x;  // t*256 + hk*32 + i
  int i = idx & 31, hh = (idx >> 5) & 7, t = idx >> 8;
  float x0 = qkv[(size_t)t * 3072 + 2048 + hh * 64 + 2 * i];
  float x1 = qkv[(size_t)t * 3072 + 2048 + hh * 64 + 2 * i + 1];
  float c = ct[t * 32 + i], s = st[t * 32 + i];
  size_t o = ((size_t)hh * 2048 + t) * 64 + 2 * i;
  kb[o] = f2bf(x0 * c - x1 * s);
  kb[o + 1] = f2bf(x0 * s + x1 * c);
}
// v: read qkv fp32 directly -> vbr (hk,t,64) + vb2 (hk,64,T) in one pass
__global__ __launch_bounds__(256) void vtrans_kernel(const float* __restrict__ qkv,
                                                     u16* __restrict__ vbr,
                                                     u16* __restrict__ vb2) {
  __shared__ u16 tl[64][72];
  int hk = blockIdx.y, t0 = blockIdx.x * 64;
  int tx = threadIdx.x & 63, ty = threadIdx.x >> 6;
#pragma unroll 4
  for (int yy = 0; yy < 16; ++yy) {
    int row = ty * 16 + yy;
    u16 b = f2bf(qkv[(size_t)(t0 + row) * 3072 + 2560 + hk * 64 + tx]);
    tl[row][tx] = b;
    vbr[((size_t)hk * 2048 + t0 + row) * 64 + tx] = b;
  }
  __syncthreads();
  u16* dst = vb2 + (size_t)hk * 64 * 2048 + t0;
#pragma unroll 4
  for (int yy = 0; yy < 16; ++yy)
    dst[(size_t)(ty * 16 + yy) * 2048 + tx] = tl[tx][ty * 16 + yy];
}

// ---------------- gates: softmax(x @ W_gate) -----------------------------------
__global__ __launch_bounds__(256) void gates_kernel(const float* __restrict__ x,
                                                    const float* __restrict__ Wg,
                                                    float* __restrict__ g) {
  int t = blockIdx.x * 4 + (threadIdx.x >> 6);
  int lane = threadIdx.x & 63;
  const float* xr = x + (size_t)t * 2048;
  float a0 = 0, a1 = 0, a2 = 0;
  for (int d = lane; d < 2048; d += 64) {
    float xv = xr[d];
    a0 = fmaf(xv, Wg[d * 3 + 0], a0);
    a1 = fmaf(xv, Wg[d * 3 + 1], a1);
    a2 = fmaf(xv, Wg[d * 3 + 2], a2);
  }
#pragma unroll
  for (int msk = 1; msk < 64; msk <<= 1) {
    a0 += __shfl_xor(a0, msk);
    a1 += __shfl_xor(a1, msk);
    a2 += __shfl_xor(a2, msk);
  }
  if (lane == 0) {
    float m = fmaxf(a0, fmaxf(a1, a2));
    float e0 = __expf(a0 - m), e1 = __expf(a1 - m), e2 = __expf(a2 - m);
    float inv = 1.f / (e0 + e1 + e2);
    g[t * 3 + 0] = e0 * inv; g[t * 3 + 1] = e1 * inv; g[t * 3 + 2] = e2 * inv;
  }
}

// ---------------- compressed-block projections ---------------------------------
__global__ __launch_bounds__(256) void cgemm_kernel(const u16* __restrict__ kB,
                                                    const u16* __restrict__ vbr,
                                                    const float* __restrict__ Wck,
                                                    const float* __restrict__ Wcv,
                                                    float* __restrict__ kc,
                                                    float* __restrict__ vc) {
  __shared__ float red[4][64];
  int b = blockIdx.x;
  bool isv = b >= 256;
  int blk = b & 255;
  const u16* src = (isv ? vbr : kB) + (size_t)blk * 4096;
  const float* W = isv ? Wcv : Wck;
  float* out = (isv ? vc : kc) + (size_t)blk * 64;
  int lane = threadIdx.x & 63, w = threadIdx.x >> 6;
  int base = w * 1024;
  float acc0 = 0.f, acc1 = 0.f;
  for (int i = 0; i < 1024; i += 8) {
    u16x8 s8 = *(const u16x8*)(src + base + i);
#pragma unroll
    for (int j = 0; j < 8; j += 2) {
      acc0 = fmaf(bf2f(s8[j]), W[(size_t)(base + i + j) * 64 + lane], acc0);
      acc1 = fmaf(bf2f(s8[j + 1]), W[(size_t)(base + i + j + 1) * 64 + lane], acc1);
    }
  }
  red[w][lane] = acc0 + acc1;
  __syncthreads();
  if (w == 0)
    out[lane] = red[0][lane] + red[1][lane] + red[2][lane] + red[3][lane];
}

// ---------------- fused 3-branch attention + gated combine ---------------------
// Round-10 math (T12 in-register softmax, verified) + REG-STAGED K/V (T14):
// no LDS, no barriers. K/V fragments load direct from global with the
// round-6-verified addressing; K double-buffered in named regs (prefetch c+1
// issued before chunk-c compute), V issued at chunk top, consumed after
// softmax (~300cyc distance). Compiler's dependence-based waitcnt handles
// correctness; waves fully independent.
__global__ __launch_bounds__(256) void attn_kernel(
    const u16* __restrict__ qb, const u16* __restrict__ kb, const u16* __restrict__ vb2,
    const float* __restrict__ kcf, const float* __restrict__ vcf,
    const float* __restrict__ gf, u16* __restrict__ comb) {
  const int tid = threadIdx.x;
  const int lane = tid & 63;
  const int lr = lane & 15;
  const int lg = lane >> 4;
  const int lk8 = lg * 8;
  const int w = tid >> 6;
  const int flat = blockIdx.y * gridDim.x + blockIdx.x;  // gridDim.x = 32
  const int swz = (flat & 7) * 128 + (flat >> 3);        // bijective: 1024 = 8*128
  const int h = swz >> 5;
  const int t0 = (swz & 31) * 64;
  const int hk = h >> 2;
  const int tw = t0 + w * 16;
  const f32x4 zero4 = {0.f, 0.f, 0.f, 0.f};
  const float LOG2E = 1.44269504f;
  const float THR = 11.5416f;  // 8 * log2(e)

  bf16x8 qf0, qf1;
  {
    const u16* qrow = qb + ((size_t)h * 2048 + (tw + lr)) * 64;
    qf0 = *(const bf16x8*)(qrow + lk8);
    qf1 = *(const bf16x8*)(qrow + 32 + lk8);
  }

  const u16* kbase = kb + (size_t)hk * 2048 * 64;   // row = key, 64 cols (d)
  const u16* vbase = vb2 + (size_t)hk * 64 * 2048;  // row = d, col = t

  f32x4 acc_s[4], acc_w[4];  // [n][r]: out[q=lr][d = n*16 + lg*4 + r]
#pragma unroll
  for (int n = 0; n < 4; ++n) { acc_s[n] = zero4; acc_w[n] = zero4; }
  float m2 = -1e30f, lsr = 0.f, lwr = 0.f;  // per-lane state for q = tw + lr

  bf16x8 kA0[4], kA1[4], kB0[4], kB1[4], vv0[4], vv1[4];
#pragma unroll
  for (int cb = 0; cb < 4; ++cb) {  // preload K(0)
    const u16* kr = kbase + (size_t)(cb * 16 + lr) * 64;
    kA0[cb] = *(const bf16x8*)(kr + lk8);
    kA1[cb] = *(const bf16x8*)(kr + 32 + lk8);
  }

#define CHUNK_BODY(cc, KC0, KC1, KN0, KN1)                                    \
  {                                                                           \
    const int s0 = (cc) * 64;                                                 \
    _Pragma("unroll") for (int n = 0; n < 4; ++n) {                           \
      const u16* vr = vbase + (size_t)(n * 16 + lr) * 2048 + s0;              \
      vv0[n] = *(const bf16x8*)(vr + lk8);                                    \
      vv1[n] = *(const bf16x8*)(vr + 32 + lk8);                               \
    }                                                                         \
    if ((cc) < 31) {                                                          \
      _Pragma("unroll") for (int cb = 0; cb < 4; ++cb) {                      \
        const u16* kr = kbase + (size_t)(s0 + 64 + cb * 16 + lr) * 64;        \
        KN0[cb] = *(const bf16x8*)(kr + lk8);                                 \
        KN1[cb] = *(const bf16x8*)(kr + 32 + lk8);                            \
      }                                                                       \
    }                                                                         \
    f32x4 sc[4];                                                              \
    __builtin_amdgcn_s_setprio(1);                                            \
    _Pragma("unroll") for (int cb = 0; cb < 4; ++cb) {                        \
      f32x4 z = zero4;                                                        \
      MFMA16(z, KC0[cb], qf0);                                                \
      MFMA16(z, KC1[cb], qf1);                                                \
      sc[cb] = z;                                                             \
    }                                                                         \
    __builtin_amdgcn_s_setprio(0);                                            \
    const bool winAct = (s0 <= tw + 15) && (s0 + 63 >= tw - 511);             \
    float mxl = -1e30f;                                                       \
    _Pragma("unroll") for (int cb = 0; cb < 4; ++cb)                          \
      _Pragma("unroll") for (int r = 0; r < 4; ++r)                           \
        mxl = fmaxf(mxl, sc[cb][r]);                                          \
    if (__any(fmaf(mxl, LOG2E, -m2) > THR)) {                                 \
      float gm = mxl;                                                         \
      gm = fmaxf(gm, __shfl_xor(gm, 16));                                     \
      gm = fmaxf(gm, __shfl_xor(gm, 32));                                     \
      float mnew = fmaxf(m2, gm * LOG2E);                                     \
      float corr = exp2_asm(m2 - mnew);                                       \
      m2 = mnew; lsr *= corr; lwr *= corr;                                    \
      _Pragma("unroll") for (int n = 0; n < 4; ++n) {                         \
        acc_s[n] *= corr; acc_w[n] *= corr;                                   \
      }                                                                       \
    }                                                                         \
    float pv[4][4];                                                           \
    _Pragma("unroll") for (int cb = 0; cb < 4; ++cb)                          \
      _Pragma("unroll") for (int r = 0; r < 4; ++r) {                         \
        pv[cb][r] = exp2_asm(fmaf(sc[cb][r], LOG2E, -m2));                    \
        lsr += pv[cb][r];                                                     \
      }                                                                       \
    if (winAct) {                                                             \
      const int dbase2 = (tw + lr) - s0 - lg * 4;                             \
      _Pragma("unroll") for (int cb = 0; cb < 4; ++cb)                        \
        _Pragma("unroll") for (int r = 0; r < 4; ++r) {                       \
          int d0 = dbase2 - 16 * cb - r;                                      \
          lwr += ((u32)d0 < 512u) ? pv[cb][r] : 0.f;                          \
        }                                                                     \
    }                                                                         \
    u32 A0 = cvtpk(pv[0][0], pv[0][1]), B0 = cvtpk(pv[0][2], pv[0][3]);       \
    u32 C0 = cvtpk(pv[1][0], pv[1][1]), D0 = cvtpk(pv[1][2], pv[1][3]);       \
    u32 A1 = cvtpk(pv[2][0], pv[2][1]), B1 = cvtpk(pv[2][2], pv[2][3]);       \
    u32 C1 = cvtpk(pv[3][0], pv[3][1]), D1 = cvtpk(pv[3][2], pv[3][3]);       \
    swapchain(A0, C0); swapchain(B0, D0);                                     \
    swapchain(A1, C1); swapchain(B1, D1);                                     \
    union { u32 wd[4]; bf16x8 v; } pf0c, pf1c;                                \
    pf0c.wd[0] = A0; pf0c.wd[1] = B0; pf0c.wd[2] = C0; pf0c.wd[3] = D0;       \
    pf1c.wd[0] = A1; pf1c.wd[1] = B1; pf1c.wd[2] = C1; pf1c.wd[3] = D1;       \
    bf16x8 pf0 = pf0c.v, pf1 = pf1c.v;                                        \
    bf16x8 aw0 = pf0, aw1 = pf1;                                              \
    if (winAct) {                                                             \
      const int base0 = (tw + lr) - (s0 + lk8);                               \
      u16x8 a0 = bc_u(pf0), a1 = bc_u(pf1);                                   \
      u16x8 z0, z1;                                                           \
      _Pragma("unroll") for (int j = 0; j < 8; ++j) {                         \
        z0[j] = ((u32)(base0 - j) < 512u) ? a0[j] : (u16)0;                   \
        z1[j] = ((u32)(base0 - 32 - j) < 512u) ? a1[j] : (u16)0;              \
      }                                                                       \
      aw0 = bc_b(z0); aw1 = bc_b(z1);                                         \
    }                                                                         \
    __builtin_amdgcn_s_setprio(1);                                            \
    _Pragma("unroll") for (int n = 0; n < 4; ++n) {                           \
      MFMA16(acc_s[n], vv0[n], pf0);                                          \
      MFMA16(acc_s[n], vv1[n], pf1);                                          \
      if (winAct) {                                                           \
        MFMA16(acc_w[n], vv0[n], aw0);                                        \
        MFMA16(acc_w[n], vv1[n], aw1);                                        \
      }                                                                       \
    }                                                                         \
    __builtin_amdgcn_s_setprio(0);                                            \
  }

#pragma unroll 1
  for (int c2 = 0; c2 < 32; c2 += 2) {
    CHUNK_BODY(c2, kA0, kA1, kB0, kB1)
    CHUNK_BODY(c2 + 1, kB0, kB1, kA0, kA1)
  }
#undef CHUNK_BODY

  // ---- compressed branch (32 keys, exact softmax; swapped operands) ----
  f32x4 accc[4];
  float lcv;
  {
    f32x4 sc0 = zero4, sc1 = zero4;
#pragma unroll
    for (int kk = 0; kk < 2; ++kk) {
      const float* kr0 = kcf + ((size_t)hk * 32 + lr) * 64 + kk * 32 + lk8;
      const float* kr1 = kcf + ((size_t)hk * 32 + 16 + lr) * 64 + kk * 32 + lk8;
      bf16x8 b0 = pack8(*(const f32x4*)kr0, *(const f32x4*)(kr0 + 4));
      bf16x8 b1 = pack8(*(const f32x4*)kr1, *(const f32x4*)(kr1 + 4));
      bf16x8 qk = kk ? qf1 : qf0;
      MFMA16(sc0, b0, qk);
      MFMA16(sc1, b1, qk);
    }
    // lane: sc0[r] = S[q=lr][key=4lg+r], sc1[r] = S[q=lr][16+4lg+r]
    float mm = -1e30f;
#pragma unroll
    for (int r = 0; r < 4; ++r) mm = fmaxf(mm, fmaxf(sc0[r], sc1[r]));
    mm = fmaxf(mm, __shfl_xor(mm, 16));
    mm = fmaxf(mm, __shfl_xor(mm, 32));
    float p0[4], p1[4];
    float ssum = 0.f;
#pragma unroll
    for (int r = 0; r < 4; ++r) {
      p0[r] = __expf(sc0[r] - mm);
      p1[r] = __expf(sc1[r] - mm);
      ssum += p0[r] + p1[r];
    }
    ssum += __shfl_xor(ssum, 16);
    ssum += __shfl_xor(ssum, 32);
    lcv = ssum;
    u32 A = cvtpk(p0[0], p0[1]), B = cvtpk(p0[2], p0[3]);
    u32 C = cvtpk(p1[0], p1[1]), D = cvtpk(p1[2], p1[3]);
    swapchain(A, C);
    swapchain(B, D);
    union { u32 wd[4]; bf16x8 v; } pc;
    pc.wd[0] = A; pc.wd[1] = B; pc.wd[2] = C; pc.wd[3] = D;
#pragma unroll
    for (int nb = 0; nb < 4; ++nb) {
      u16x8 bb;
#pragma unroll
      for (int j = 0; j < 8; ++j)
        bb[j] = f2bf(vcf[((size_t)hk * 32 + lk8 + j) * 64 + nb * 16 + lr]);
      f32x4 z = zero4;
      MFMA16(z, bc_b(bb), pc.v);
      accc[nb] = z;
    }
  }

  // ---- gated combine, write bf16 comb (T, H*D); lane owns q = tw+lr ----
  float ls = lsr;
  ls += __shfl_xor(ls, 16);
  ls += __shfl_xor(ls, 32);
  float lw = lwr;
  lw += __shfl_xor(lw, 16);
  lw += __shfl_xor(lw, 32);
  {
    const int t = tw + lr;
    float g0 = gf[t * 3 + 0], g1 = gf[t * 3 + 1], g2 = gf[t * 3 + 2];
    float wc_ = g0 / lcv;
    float ws_ = g1 / ls;
    float ww_ = g2 / lw;
#pragma unroll
    for (int n = 0; n < 4; ++n) {
      u16x4 o;
#pragma unroll
      for (int r = 0; r < 4; ++r)
        o[r] = f2bf(accc[n][r] * wc_ + acc_s[n][r] * ws_ + acc_w[n][r] * ww_);
      *(u16x4*)&comb[(size_t)t * 2048 + h * 64 + n * 16 + lg * 4] = o;
    }
  }
}

// =============================================================================
extern "C" void kernel_launch(void* const* d_in, const int* in_sizes, int n_in,
                              void* d_out, int out_size, void* d_ws, size_t ws_size,
                              hipStream_t stream) {
  (void)in_sizes; (void)n_in; (void)out_size;
  const float* x   = (const float*)d_in[0];
  const float* Wq  = (const float*)d_in[1];
  const float* Wk  = (const float*)d_in[2];
  const float* Wv  = (const float*)d_in[3];
  const float* Wo  = (const float*)d_in[4];
  const float* Wck = (const float*)d_in[5];
  const float* Wcv = (const float*)d_in[6];
  const float* Wg  = (const float*)d_in[8];
  float* out = (float*)d_out;
  char* ws = (char*)d_ws;

  constexpr size_t OXB   = 0;                    // x bf16        (T x 2048)
  constexpr size_t OWT   = OXB  + 8388608;       // [Wq|Wk|Wv]T bf16 (3072x2048)
  constexpr size_t OWOT  = OWT  + 12582912;      // WoT bf16      (2048x2048)
  constexpr size_t OQKV  = OWOT + 8388608;       // qkv fp32      (T x 3072)
  constexpr size_t OQB   = OQKV + 25165824;      // q bf16 roped+scaled (H,T,64)
  constexpr size_t OKB   = OQB  + 8388608;       // k bf16 roped  (HKV,T,64)
  constexpr size_t OVB   = OKB  + 2097152;       // v bf16        (HKV,64,T)
  constexpr size_t OCT   = OVB  + 2097152;       // cos table
  constexpr size_t OST   = OCT  + 262144;        // sin table
  constexpr size_t OKC   = OST  + 262144;        // kc fp32
  constexpr size_t OVC   = OKC  + 65536;         // vc fp32
  constexpr size_t OG    = OVC  + 65536;         // gates fp32
  constexpr size_t OCOMB = OG   + 24576;         // comb bf16; vbr aliases here
  constexpr size_t TOTAL = OCOMB + 8388608;
  if (ws_size < TOTAL) return;

  u16* xb    = (u16*)(ws + OXB);
  u16* WT    = (u16*)(ws + OWT);
  u16* WoT   = (u16*)(ws + OWOT);
  float* qkv = (float*)(ws + OQKV);
  u16* qB    = (u16*)(ws + OQB);
  u16* kB    = (u16*)(ws + OKB);
  u16* vB2   = (u16*)(ws + OVB);
  float* ct  = (float*)(ws + OCT);
  float* st  = (float*)(ws + OST);
  float* kc  = (float*)(ws + OKC);
  float* vc  = (float*)(ws + OVC);
  float* gg  = (float*)(ws + OG);
  u16* comb  = (u16*)(ws + OCOMB);
  u16* vbr   = comb;  // alias: consumed by cgemm BEFORE attn writes comb

  freqs_kernel<<<dim3(256), dim3(256), 0, stream>>>(ct, st);
  cvt_x_kernel<<<dim3(4096), dim3(256), 0, stream>>>(x, xb);
  trcvt_kernel<<<dim3(1024), dim3(256), 0, stream>>>(Wq, WT, 2048, 2048);
  trcvt_kernel<<<dim3(256),  dim3(256), 0, stream>>>(Wk, WT + (size_t)2048 * 2048, 2048, 512);
  trcvt_kernel<<<dim3(256),  dim3(256), 0, stream>>>(Wv, WT + (size_t)2560 * 2048, 2048, 512);
  trcvt_kernel<<<dim3(1024), dim3(256), 0, stream>>>(Wo, WoT, 2048, 2048);

  gemm_bt_kernel<<<dim3(16, 24), dim3(256), 0, stream>>>(xb, WT, qkv, 2048, 3072, 2048);

  rope_q_kernel<<<dim3(8192), dim3(256), 0, stream>>>(qkv, ct, st, qB);
  rope_k_kernel<<<dim3(2048), dim3(256), 0, stream>>>(qkv, ct, st, kB);
  vtrans_kernel<<<dim3(32, 8), dim3(256), 0, stream>>>(qkv, vbr, vB2);
  gates_kernel<<<dim3(512), dim3(256), 0, stream>>>(x, Wg, gg);

  cgemm_kernel<<<dim3(512), dim3(256), 0, stream>>>(kB, vbr, Wck, Wcv, kc, vc);

  attn_kernel<<<dim3(32, 32), dim3(256), 0, stream>>>(qB, kB, vB2, kc, vc, gg, comb);

  gemm_bt_kernel<<<dim3(16, 16), dim3(256), 0, stream>>>(comb, WoT, out, 2048, 2048, 2048);
}

// Round 12
// 261.138 us; speedup vs baseline: 1.5560x; 1.5560x over previous
//
#include <hip/hip_runtime.h>
#include <cmath>

typedef unsigned short u16;
typedef unsigned int u32;
typedef __attribute__((ext_vector_type(8))) __bf16 bf16x8;
typedef __attribute__((ext_vector_type(8))) u16 u16x8;
typedef __attribute__((ext_vector_type(4))) float f32x4;
typedef __attribute__((ext_vector_type(4))) u16 u16x4;

#define MFMA16(acc, a, b) (acc) = __builtin_amdgcn_mfma_f32_16x16x32_bf16((a), (b), (acc), 0, 0, 0)

__device__ __forceinline__ u16 f2bf(float x) {
  union { float f; u32 u; } c; c.f = x;
  u32 r = (c.u + 0x7FFFu + ((c.u >> 16) & 1u)) >> 16;
  return (u16)r;
}
__device__ __forceinline__ float bf2f(u16 b) {
  union { u32 u; float f; } c; c.u = ((u32)b) << 16;
  return c.f;
}
__device__ __forceinline__ void gload16(const u16* g, u16* l) {
  __builtin_amdgcn_global_load_lds(
      (const __attribute__((address_space(1))) void*)(g),
      (__attribute__((address_space(3))) void*)(l), 16, 0, 0);
}
__device__ __forceinline__ float exp2_asm(float x) {
  float r;
  asm("v_exp_f32 %0, %1\n\ts_nop 0" : "=v"(r) : "v"(x));
  return r;
}
__device__ __forceinline__ u32 cvtpk(float a, float b) {
  u32 r;
  asm("v_cvt_pk_bf16_f32 %0, %1, %2" : "=v"(r) : "v"(a), "v"(b));
  return r;
}
__device__ __forceinline__ u16x8 bc_u(bf16x8 v) { union { bf16x8 b; u16x8 u; } c; c.b = v; return c.u; }
__device__ __forceinline__ bf16x8 bc_b(u16x8 v) { union { u16x8 u; bf16x8 b; } c; c.u = v; return c.b; }
__device__ __forceinline__ bf16x8 pack8(f32x4 a, f32x4 b) {
  union { u32 w[4]; bf16x8 v; } c;
  c.w[0] = cvtpk(a[0], a[1]);
  c.w[1] = cvtpk(a[2], a[3]);
  c.w[2] = cvtpk(b[0], b[1]);
  c.w[3] = cvtpk(b[2], b[3]);
  return c.v;
}
// chain: after swap32 then swap16, a = frag word pair {keys +0,+1}-per-quadrant,
// c = {keys +4,+5} (derivation verified in round 10)
__device__ __forceinline__ void swapchain(u32& a, u32& c) {
  asm("v_permlane32_swap_b32 %0, %1" : "+v"(a), "+v"(c));
  asm("v_permlane16_swap_b32 %0, %1" : "+v"(a), "+v"(c));
}

// ---------------- freqs table --------------------------------------------------
__global__ void freqs_kernel(float* __restrict__ ct, float* __restrict__ st) {
  int idx = blockIdx.x * 256 + threadIdx.x;  // t*32 + i
  int t = idx >> 5, i = idx & 31;
  float inv = 1.0f / powf(10000.0f, (float)i / 32.0f);
  float a = (float)t * inv;
  float sv, cv;
  sincosf(a, &sv, &cv);
  ct[idx] = cv;
  st[idx] = sv;
}

// ---------------- fp32 -> bf16 flat convert (x) --------------------------------
__global__ void cvt_x_kernel(const float* __restrict__ in, u16* __restrict__ out) {
  int idx = (blockIdx.x * 256 + threadIdx.x) * 4;
  f32x4 v = *(const f32x4*)(in + idx);
  u16x4 o;
  o[0] = f2bf(v[0]); o[1] = f2bf(v[1]); o[2] = f2bf(v[2]); o[3] = f2bf(v[3]);
  *(u16x4*)(out + idx) = o;
}

// ---------------- transpose + convert: Wt[n*K+k] = bf16(W[k*N+n]) --------------
__global__ __launch_bounds__(256) void trcvt_kernel(const float* __restrict__ W,
                                                    u16* __restrict__ Wt, int K, int N) {
  __shared__ u16 t_lds[64][65];
  int ntx = N >> 6;
  int kt = (blockIdx.x / ntx) * 64, nt = (blockIdx.x % ntx) * 64;
  int tx = threadIdx.x & 63, ty4 = threadIdx.x >> 6;
#pragma unroll 4
  for (int yy = 0; yy < 16; ++yy) {
    int k = kt + ty4 * 16 + yy;
    t_lds[ty4 * 16 + yy][tx] = f2bf(W[(size_t)k * N + nt + tx]);
  }
  __syncthreads();
#pragma unroll 4
  for (int yy = 0; yy < 16; ++yy) {
    int n = nt + ty4 * 16 + yy;
    Wt[(size_t)n * K + kt + tx] = t_lds[tx][ty4 * 16 + yy];
  }
}

// ---------------- m97-structure bf16 MFMA GEMM + XCD swizzle (o-proj) ----------
__global__ __launch_bounds__(256) void gemm_bt_kernel(const u16* __restrict__ A,
                                                      const u16* __restrict__ Bt,
                                                      float* __restrict__ C,
                                                      int M, int N, int K) {
  __shared__ __align__(16) u16 As[128 * 64];
  __shared__ __align__(16) u16 Bs[128 * 64];
  const int tid = threadIdx.x;
  const int lane = tid & 63;
  const int w = tid >> 6;
  const int lr = lane & 15;
  const int lg = lane >> 4;
  const int lk8 = lg * 8;
  const int gx = gridDim.x;
  const int nwg = gx * gridDim.y;
  const int flat = blockIdx.y * gx + blockIdx.x;
  const int qq = nwg >> 3;
  const int swz = (flat & 7) * qq + (flat >> 3);
  const int brow = (swz % gx) * 128;
  const int bcol = (swz / gx) * 128;
  const int wr = (w >> 1) * 64;
  const int wc = (w & 1) * 64;

  const f32x4 zero4 = {0.f, 0.f, 0.f, 0.f};
  f32x4 acc[4][4];
#pragma unroll
  for (int m = 0; m < 4; ++m)
#pragma unroll
    for (int n = 0; n < 4; ++n) acc[m][n] = zero4;

  const int srow = tid >> 3;
  const int scol = (tid & 7) * 8;
  const u16* Ab = A + (size_t)(brow + srow) * K + scol;
  const u16* Bb = Bt + (size_t)(bcol + srow) * K + scol;

  for (int k0 = 0; k0 < K; k0 += 64) {
    __syncthreads();
#pragma unroll
    for (int it = 0; it < 4; ++it) {
      gload16(Ab + (size_t)it * 32 * K + k0, &As[tid * 8 + it * 2048]);
      gload16(Bb + (size_t)it * 32 * K + k0, &Bs[tid * 8 + it * 2048]);
    }
    __syncthreads();
#pragma unroll
    for (int kk = 0; kk < 2; ++kk) {
      bf16x8 af[4], bv[4];
#pragma unroll
      for (int m = 0; m < 4; ++m)
        af[m] = *(const bf16x8*)&As[(wr + m * 16 + lr) * 64 + kk * 32 + lk8];
#pragma unroll
      for (int n = 0; n < 4; ++n)
        bv[n] = *(const bf16x8*)&Bs[(wc + n * 16 + lr) * 64 + kk * 32 + lk8];
#pragma unroll
      for (int m = 0; m < 4; ++m)
#pragma unroll
        for (int n = 0; n < 4; ++n) MFMA16(acc[m][n], af[m], bv[n]);
    }
  }
#pragma unroll
  for (int m = 0; m < 4; ++m) {
#pragma unroll
    for (int rr = 0; rr < 4; ++rr) {
      int row = brow + wr + m * 16 + lg * 4 + rr;
#pragma unroll
      for (int n = 0; n < 4; ++n)
        C[(size_t)row * N + bcol + wc + n * 16 + lr] = acc[m][n][rr];
    }
  }
}

// ---------------- qkv GEMM with fused RoPE / layout epilogue -------------------
// Same verified GEMM body (M=2048,N=3072,K=2048); epilogue applies RoPE to
// q/k via lane-pair shfl (partner col = lane lr^1) and writes q/k/v directly
// in final bf16 layouts. Each 128-wide col tile is purely q, k, or v
// (2048, 2560 are tile-aligned) -> wave-uniform branch.
__global__ __launch_bounds__(256) void gemm_qkv_kernel(
    const u16* __restrict__ A, const u16* __restrict__ Bt,
    const float* __restrict__ ct, const float* __restrict__ st,
    u16* __restrict__ qB, u16* __restrict__ kB,
    u16* __restrict__ vbr, u16* __restrict__ vb2) {
  __shared__ __align__(16) u16 As[128 * 64];
  __shared__ __align__(16) u16 Bs[128 * 64];
  const int K = 2048;
  const int tid = threadIdx.x;
  const int lane = tid & 63;
  const int w = tid >> 6;
  const int lr = lane & 15;
  const int lg = lane >> 4;
  const int lk8 = lg * 8;
  const int gx = gridDim.x;  // 16
  const int nwg = gx * gridDim.y;
  const int flat = blockIdx.y * gx + blockIdx.x;
  const int qq = nwg >> 3;
  const int swz = (flat & 7) * qq + (flat >> 3);
  const int brow = (swz % gx) * 128;
  const int bcol = (swz / gx) * 128;
  const int wr = (w >> 1) * 64;
  const int wc = (w & 1) * 64;

  const f32x4 zero4 = {0.f, 0.f, 0.f, 0.f};
  f32x4 acc[4][4];
#pragma unroll
  for (int m = 0; m < 4; ++m)
#pragma unroll
    for (int n = 0; n < 4; ++n) acc[m][n] = zero4;

  const int srow = tid >> 3;
  const int scol = (tid & 7) * 8;
  const u16* Ab = A + (size_t)(brow + srow) * K + scol;
  const u16* Bb = Bt + (size_t)(bcol + srow) * K + scol;

  for (int k0 = 0; k0 < K; k0 += 64) {
    __syncthreads();
#pragma unroll
    for (int it = 0; it < 4; ++it) {
      gload16(Ab + (size_t)it * 32 * K + k0, &As[tid * 8 + it * 2048]);
      gload16(Bb + (size_t)it * 32 * K + k0, &Bs[tid * 8 + it * 2048]);
    }
    __syncthreads();
#pragma unroll
    for (int kk = 0; kk < 2; ++kk) {
      bf16x8 af[4], bv[4];
#pragma unroll
      for (int m = 0; m < 4; ++m)
        af[m] = *(const bf16x8*)&As[(wr + m * 16 + lr) * 64 + kk * 32 + lk8];
#pragma unroll
      for (int n = 0; n < 4; ++n)
        bv[n] = *(const bf16x8*)&Bs[(wc + n * 16 + lr) * 64 + kk * 32 + lk8];
#pragma unroll
      for (int m = 0; m < 4; ++m)
#pragma unroll
        for (int n = 0; n < 4; ++n) MFMA16(acc[m][n], af[m], bv[n]);
    }
  }

  // ---- fused epilogue ----
  const int colbase = bcol + wc;  // wave-uniform; tile is purely q, k, or v
  if (colbase < 2048) {
    // q: rope + 1/8 scale -> qB (H, T, 64)
#pragma unroll
    for (int m = 0; m < 4; ++m)
#pragma unroll
      for (int n = 0; n < 4; ++n) {
        const int c = colbase + n * 16 + lr;
        const int hd = c >> 6, d = c & 63, i = d >> 1;
        const float sgn = (c & 1) ? 1.f : -1.f;
#pragma unroll
        for (int rr = 0; rr < 4; ++rr) {
          int t = brow + wr + m * 16 + lg * 4 + rr;
          float v = acc[m][n][rr];
          float p = __shfl_xor(v, 1);
          float co = ct[t * 32 + i], si = st[t * 32 + i];
          float o = fmaf(p, sgn * si, v * co) * 0.125f;
          qB[(size_t)hd * 131072 + (size_t)t * 64 + d] = f2bf(o);
        }
      }
  } else if (colbase < 2560) {
    // k: rope -> kB (HKV, T, 64)
#pragma unroll
    for (int m = 0; m < 4; ++m)
#pragma unroll
      for (int n = 0; n < 4; ++n) {
        const int c2 = colbase + n * 16 + lr - 2048;
        const int hk = c2 >> 6, d = c2 & 63, i = d >> 1;
        const float sgn = (c2 & 1) ? 1.f : -1.f;
#pragma unroll
        for (int rr = 0; rr < 4; ++rr) {
          int t = brow + wr + m * 16 + lg * 4 + rr;
          float v = acc[m][n][rr];
          float p = __shfl_xor(v, 1);
          float co = ct[t * 32 + i], si = st[t * 32 + i];
          float o = fmaf(p, sgn * si, v * co);
          kB[(size_t)hk * 131072 + (size_t)t * 64 + d] = f2bf(o);
        }
      }
  } else {
    // v: plain convert -> vbr (HKV,T,64) + vb2 (HKV,64,T)
#pragma unroll
    for (int m = 0; m < 4; ++m)
#pragma unroll
      for (int n = 0; n < 4; ++n) {
        const int c2 = colbase + n * 16 + lr - 2560;
        const int hk = c2 >> 6, d = c2 & 63;
#pragma unroll
        for (int rr = 0; rr < 4; ++rr) {
          int t = brow + wr + m * 16 + lg * 4 + rr;
          u16 b = f2bf(acc[m][n][rr]);
          vbr[(size_t)hk * 131072 + (size_t)t * 64 + d] = b;
          vb2[(size_t)hk * 131072 + (size_t)d * 2048 + t] = b;
        }
      }
  }
}

// ---------------- gates: softmax(x @ W_gate) -----------------------------------
__global__ __launch_bounds__(256) void gates_kernel(const float* __restrict__ x,
                                                    const float* __restrict__ Wg,
                                                    float* __restrict__ g) {
  int t = blockIdx.x * 4 + (threadIdx.x >> 6);
  int lane = threadIdx.x & 63;
  const float* xr = x + (size_t)t * 2048;
  float a0 = 0, a1 = 0, a2 = 0;
  for (int d = lane; d < 2048; d += 64) {
    float xv = xr[d];
    a0 = fmaf(xv, Wg[d * 3 + 0], a0);
    a1 = fmaf(xv, Wg[d * 3 + 1], a1);
    a2 = fmaf(xv, Wg[d * 3 + 2], a2);
  }
#pragma unroll
  for (int msk = 1; msk < 64; msk <<= 1) {
    a0 += __shfl_xor(a0, msk);
    a1 += __shfl_xor(a1, msk);
    a2 += __shfl_xor(a2, msk);
  }
  if (lane == 0) {
    float m = fmaxf(a0, fmaxf(a1, a2));
    float e0 = __expf(a0 - m), e1 = __expf(a1 - m), e2 = __expf(a2 - m);
    float inv = 1.f / (e0 + e1 + e2);
    g[t * 3 + 0] = e0 * inv; g[t * 3 + 1] = e1 * inv; g[t * 3 + 2] = e2 * inv;
  }
}

// ---------------- compressed-block projections ---------------------------------
__global__ __launch_bounds__(256) void cgemm_kernel(const u16* __restrict__ kB,
                                                    const u16* __restrict__ vbr,
                                                    const float* __restrict__ Wck,
                                                    const float* __restrict__ Wcv,
                                                    float* __restrict__ kc,
                                                    float* __restrict__ vc) {
  __shared__ float red[4][64];
  int b = blockIdx.x;
  bool isv = b >= 256;
  int blk = b & 255;
  const u16* src = (isv ? vbr : kB) + (size_t)blk * 4096;
  const float* W = isv ? Wcv : Wck;
  float* out = (isv ? vc : kc) + (size_t)blk * 64;
  int lane = threadIdx.x & 63, w = threadIdx.x >> 6;
  int base = w * 1024;
  float acc0 = 0.f, acc1 = 0.f;
  for (int i = 0; i < 1024; i += 8) {
    u16x8 s8 = *(const u16x8*)(src + base + i);
#pragma unroll
    for (int j = 0; j < 8; j += 2) {
      acc0 = fmaf(bf2f(s8[j]), W[(size_t)(base + i + j) * 64 + lane], acc0);
      acc1 = fmaf(bf2f(s8[j + 1]), W[(size_t)(base + i + j + 1) * 64 + lane], acc1);
    }
  }
  red[w][lane] = acc0 + acc1;
  __syncthreads();
  if (w == 0)
    out[lane] = red[0][lane] + red[1][lane] + red[2][lane] + red[3][lane];
}

// ---------------- fused 3-branch attention + gated combine ---------------------
// ROUND-10 VERIFIED KERNEL (byte-identical): T12 swapped-QK^T in-register
// softmax, LDS-staged double-buffered K/V, bijective XCD swizzle. LDS 32KB.
__global__ __launch_bounds__(256) void attn_kernel(
    const u16* __restrict__ qb, const u16* __restrict__ kb, const u16* __restrict__ vb2,
    const float* __restrict__ kcf, const float* __restrict__ vcf,
    const float* __restrict__ gf, u16* __restrict__ comb) {
  __shared__ __align__(16) u16 k_lds[2][64 * 64];
  __shared__ __align__(16) u16 vt_lds[2][64 * 64];

  const int tid = threadIdx.x;
  const int lane = tid & 63;
  const int lr = lane & 15;
  const int lg = lane >> 4;
  const int lk8 = lg * 8;
  const int w = tid >> 6;
  const int flat = blockIdx.y * gridDim.x + blockIdx.x;  // gridDim.x = 32
  const int swz = (flat & 7) * 128 + (flat >> 3);        // bijective: 1024 = 8*128
  const int h = swz >> 5;
  const int t0 = (swz & 31) * 64;
  const int hk = h >> 2;
  const int tw = t0 + w * 16;
  const f32x4 zero4 = {0.f, 0.f, 0.f, 0.f};
  const float LOG2E = 1.44269504f;
  const float THR = 11.5416f;  // 8 * log2(e)

  bf16x8 qf0, qf1;
  {
    const u16* qrow = qb + ((size_t)h * 2048 + (tw + lr)) * 64;
    qf0 = *(const bf16x8*)(qrow + lk8);
    qf1 = *(const bf16x8*)(qrow + 32 + lk8);
  }

  // K/V staging: identical to round 9 (verified)
  const int lin1 = 256 + tid;
  const int row0 = tid >> 3, sl0 = (tid & 7) ^ (row0 & 7);
  const int row1 = lin1 >> 3, sl1 = (lin1 & 7) ^ (row1 & 7);
  const u16* kS0 = kb + ((size_t)hk * 2048 + row0) * 64 + sl0 * 8;
  const u16* kS1 = kb + ((size_t)hk * 2048 + row1) * 64 + sl1 * 8;
  const u16* vS0 = vb2 + ((size_t)hk * 64 + row0) * 2048 + sl0 * 8;
  const u16* vS1 = vb2 + ((size_t)hk * 64 + row1) * 2048 + sl1 * 8;

  const int sA = ((0 + lg) ^ (lr & 7)) * 8;
  const int sB = ((4 + lg) ^ (lr & 7)) * 8;

  f32x4 acc_s[4], acc_w[4];  // [n][r]: out[q=lr][d = n*16 + lg*4 + r]
#pragma unroll
  for (int n = 0; n < 4; ++n) { acc_s[n] = zero4; acc_w[n] = zero4; }
  float m2 = -1e30f, lsr = 0.f, lwr = 0.f;  // per-lane state for q = tw + lr

#define STAGE(cc)                                                      \
  {                                                                    \
    const int b_ = (cc) & 1;                                           \
    gload16(kS0 + (size_t)(cc) * 4096, &k_lds[b_][tid * 8]);           \
    gload16(kS1 + (size_t)(cc) * 4096, &k_lds[b_][2048 + tid * 8]);    \
    gload16(vS0 + (cc) * 64, &vt_lds[b_][tid * 8]);                    \
    gload16(vS1 + (cc) * 64, &vt_lds[b_][2048 + tid * 8]);             \
  }

  STAGE(0);
  __syncthreads();

#pragma unroll 1
  for (int c = 0; c < 32; ++c) {
    const int s0 = c * 64;
    const u16* kbuf = k_lds[c & 1];
    const u16* vbuf = vt_lds[c & 1];
    if (c < 31) STAGE(c + 1);  // prefetch: overlaps with all compute below

    // swapped QK^T: sc[cb][r] = S[q=lr][key = s0 + 16cb + 4lg + r]
    f32x4 sc[4];
    __builtin_amdgcn_s_setprio(1);
#pragma unroll
    for (int cb = 0; cb < 4; ++cb) {
      f32x4 z = zero4;
      const int rb = (cb * 16 + lr) * 64;
      bf16x8 b0 = *(const bf16x8*)&kbuf[rb + sA];
      bf16x8 b1 = *(const bf16x8*)&kbuf[rb + sB];
      MFMA16(z, b0, qf0);
      MFMA16(z, b1, qf1);
      sc[cb] = z;
    }
    __builtin_amdgcn_s_setprio(0);

    const bool winAct = (s0 <= tw + 15) && (s0 + 63 >= tw - 511);

    // rare-rescale check (T13, exact): lane-local 16-max
    float mxl = -1e30f;
#pragma unroll
    for (int cb = 0; cb < 4; ++cb)
#pragma unroll
      for (int r = 0; r < 4; ++r) mxl = fmaxf(mxl, sc[cb][r]);
    if (__any(fmaf(mxl, LOG2E, -m2) > THR)) {
      float gm = mxl;
      gm = fmaxf(gm, __shfl_xor(gm, 16));
      gm = fmaxf(gm, __shfl_xor(gm, 32));
      float mnew = fmaxf(m2, gm * LOG2E);
      float corr = exp2_asm(m2 - mnew);
      m2 = mnew;
      lsr *= corr;
      lwr *= corr;
#pragma unroll
      for (int n = 0; n < 4; ++n) { acc_s[n] *= corr; acc_w[n] *= corr; }
    }

    // P in registers
    float pv[4][4];
#pragma unroll
    for (int cb = 0; cb < 4; ++cb)
#pragma unroll
      for (int r = 0; r < 4; ++r) {
        pv[cb][r] = exp2_asm(fmaf(sc[cb][r], LOG2E, -m2));
        lsr += pv[cb][r];
      }
    if (winAct) {
      const int dbase2 = (tw + lr) - s0 - lg * 4;
#pragma unroll
      for (int cb = 0; cb < 4; ++cb)
#pragma unroll
        for (int r = 0; r < 4; ++r) {
          int d0 = dbase2 - 16 * cb - r;
          lwr += ((u32)d0 < 512u) ? pv[cb][r] : 0.f;
        }
    }

    // build PV B-frags in-register (no LDS)
    u32 A0 = cvtpk(pv[0][0], pv[0][1]), B0 = cvtpk(pv[0][2], pv[0][3]);
    u32 C0 = cvtpk(pv[1][0], pv[1][1]), D0 = cvtpk(pv[1][2], pv[1][3]);
    u32 A1 = cvtpk(pv[2][0], pv[2][1]), B1 = cvtpk(pv[2][2], pv[2][3]);
    u32 C1 = cvtpk(pv[3][0], pv[3][1]), D1 = cvtpk(pv[3][2], pv[3][3]);
    swapchain(A0, C0);
    swapchain(B0, D0);
    swapchain(A1, C1);
    swapchain(B1, D1);
    union { u32 wd[4]; bf16x8 v; } pf0c, pf1c;
    pf0c.wd[0] = A0; pf0c.wd[1] = B0; pf0c.wd[2] = C0; pf0c.wd[3] = D0;
    pf1c.wd[0] = A1; pf1c.wd[1] = B1; pf1c.wd[2] = C1; pf1c.wd[3] = D1;
    bf16x8 pf0 = pf0c.v, pf1 = pf1c.v;

    bf16x8 aw0 = pf0, aw1 = pf1;
    if (winAct) {  // mask P frag elements: elem j of pf0 = key s0+lk8+j, q = tw+lr
      const int base0 = (tw + lr) - (s0 + lk8);
      u16x8 a0 = bc_u(pf0), a1 = bc_u(pf1);
      u16x8 z0, z1;
#pragma unroll
      for (int j = 0; j < 8; ++j) {
        z0[j] = ((u32)(base0 - j) < 512u) ? a0[j] : (u16)0;
        z1[j] = ((u32)(base0 - 32 - j) < 512u) ? a1[j] : (u16)0;
      }
      aw0 = bc_b(z0);
      aw1 = bc_b(z1);
    }

    // PV swapped: mfma(V^T, P) -> acc[n][r] = out[q=lr][d = n*16+lg*4+r]
    __builtin_amdgcn_s_setprio(1);
#pragma unroll
    for (int n = 0; n < 4; ++n) {
      const int rb = (n * 16 + lr) * 64;
      bf16x8 bv0 = *(const bf16x8*)&vbuf[rb + sA];
      bf16x8 bv1 = *(const bf16x8*)&vbuf[rb + sB];
      MFMA16(acc_s[n], bv0, pf0);
      MFMA16(acc_s[n], bv1, pf1);
      if (winAct) {
        MFMA16(acc_w[n], bv0, aw0);
        MFMA16(acc_w[n], bv1, aw1);
      }
    }
    __builtin_amdgcn_s_setprio(0);

    __syncthreads();  // implicit vmcnt drain: covers STAGE(c+1), issued pre-compute
  }
#undef STAGE

  // ---- compressed branch (32 keys, exact softmax; swapped operands) ----
  f32x4 accc[4];
  float lcv;
  {
    f32x4 sc0 = zero4, sc1 = zero4;
#pragma unroll
    for (int kk = 0; kk < 2; ++kk) {
      const float* kr0 = kcf + ((size_t)hk * 32 + lr) * 64 + kk * 32 + lk8;
      const float* kr1 = kcf + ((size_t)hk * 32 + 16 + lr) * 64 + kk * 32 + lk8;
      bf16x8 b0 = pack8(*(const f32x4*)kr0, *(const f32x4*)(kr0 + 4));
      bf16x8 b1 = pack8(*(const f32x4*)kr1, *(const f32x4*)(kr1 + 4));
      bf16x8 qk = kk ? qf1 : qf0;
      MFMA16(sc0, b0, qk);
      MFMA16(sc1, b1, qk);
    }
    // lane: sc0[r] = S[q=lr][key=4lg+r], sc1[r] = S[q=lr][16+4lg+r]
    float mm = -1e30f;
#pragma unroll
    for (int r = 0; r < 4; ++r) mm = fmaxf(mm, fmaxf(sc0[r], sc1[r]));
    mm = fmaxf(mm, __shfl_xor(mm, 16));
    mm = fmaxf(mm, __shfl_xor(mm, 32));
    float p0[4], p1[4];
    float ssum = 0.f;
#pragma unroll
    for (int r = 0; r < 4; ++r) {
      p0[r] = __expf(sc0[r] - mm);
      p1[r] = __expf(sc1[r] - mm);
      ssum += p0[r] + p1[r];
    }
    ssum += __shfl_xor(ssum, 16);
    ssum += __shfl_xor(ssum, 32);
    lcv = ssum;
    u32 A = cvtpk(p0[0], p0[1]), B = cvtpk(p0[2], p0[3]);
    u32 C = cvtpk(p1[0], p1[1]), D = cvtpk(p1[2], p1[3]);
    swapchain(A, C);
    swapchain(B, D);
    union { u32 wd[4]; bf16x8 v; } pc;
    pc.wd[0] = A; pc.wd[1] = B; pc.wd[2] = C; pc.wd[3] = D;
#pragma unroll
    for (int nb = 0; nb < 4; ++nb) {
      u16x8 bb;
#pragma unroll
      for (int j = 0; j < 8; ++j)
        bb[j] = f2bf(vcf[((size_t)hk * 32 + lk8 + j) * 64 + nb * 16 + lr]);
      f32x4 z = zero4;
      MFMA16(z, bc_b(bb), pc.v);
      accc[nb] = z;
    }
  }

  // ---- gated combine, write bf16 comb (T, H*D); lane owns q = tw+lr ----
  float ls = lsr;
  ls += __shfl_xor(ls, 16);
  ls += __shfl_xor(ls, 32);
  float lw = lwr;
  lw += __shfl_xor(lw, 16);
  lw += __shfl_xor(lw, 32);
  {
    const int t = tw + lr;
    float g0 = gf[t * 3 + 0], g1 = gf[t * 3 + 1], g2 = gf[t * 3 + 2];
    float wc_ = g0 / lcv;
    float ws_ = g1 / ls;
    float ww_ = g2 / lw;
#pragma unroll
    for (int n = 0; n < 4; ++n) {
      u16x4 o;
#pragma unroll
      for (int r = 0; r < 4; ++r)
        o[r] = f2bf(accc[n][r] * wc_ + acc_s[n][r] * ws_ + acc_w[n][r] * ww_);
      *(u16x4*)&comb[(size_t)t * 2048 + h * 64 + n * 16 + lg * 4] = o;
    }
  }
}

// =============================================================================
extern "C" void kernel_launch(void* const* d_in, const int* in_sizes, int n_in,
                              void* d_out, int out_size, void* d_ws, size_t ws_size,
                              hipStream_t stream) {
  (void)in_sizes; (void)n_in; (void)out_size;
  const float* x   = (const float*)d_in[0];
  const float* Wq  = (const float*)d_in[1];
  const float* Wk  = (const float*)d_in[2];
  const float* Wv  = (const float*)d_in[3];
  const float* Wo  = (const float*)d_in[4];
  const float* Wck = (const float*)d_in[5];
  const float* Wcv = (const float*)d_in[6];
  const float* Wg  = (const float*)d_in[8];
  float* out = (float*)d_out;
  char* ws = (char*)d_ws;

  constexpr size_t OXB   = 0;                    // x bf16        (T x 2048)
  constexpr size_t OWT   = OXB  + 8388608;       // [Wq|Wk|Wv]T bf16 (3072x2048)
  constexpr size_t OWOT  = OWT  + 12582912;      // WoT bf16      (2048x2048)
  constexpr size_t OQKV  = OWOT + 8388608;       // (unused now; kept for layout)
  constexpr size_t OQB   = OQKV + 25165824;      // q bf16 roped+scaled (H,T,64)
  constexpr size_t OKB   = OQB  + 8388608;       // k bf16 roped  (HKV,T,64)
  constexpr size_t OVB   = OKB  + 2097152;       // v bf16        (HKV,64,T)
  constexpr size_t OCT   = OVB  + 2097152;       // cos table
  constexpr size_t OST   = OCT  + 262144;        // sin table
  constexpr size_t OKC   = OST  + 262144;        // kc fp32
  constexpr size_t OVC   = OKC  + 65536;         // vc fp32
  constexpr size_t OG    = OVC  + 65536;         // gates fp32
  constexpr size_t OCOMB = OG   + 24576;         // comb bf16; vbr aliases here
  constexpr size_t TOTAL = OCOMB + 8388608;
  if (ws_size < TOTAL) return;

  u16* xb    = (u16*)(ws + OXB);
  u16* WT    = (u16*)(ws + OWT);
  u16* WoT   = (u16*)(ws + OWOT);
  u16* qB    = (u16*)(ws + OQB);
  u16* kB    = (u16*)(ws + OKB);
  u16* vB2   = (u16*)(ws + OVB);
  float* ct  = (float*)(ws + OCT);
  float* st  = (float*)(ws + OST);
  float* kc  = (float*)(ws + OKC);
  float* vc  = (float*)(ws + OVC);
  float* gg  = (float*)(ws + OG);
  u16* comb  = (u16*)(ws + OCOMB);
  u16* vbr   = comb;  // alias: consumed by cgemm BEFORE attn writes comb

  freqs_kernel<<<dim3(256), dim3(256), 0, stream>>>(ct, st);
  cvt_x_kernel<<<dim3(4096), dim3(256), 0, stream>>>(x, xb);
  trcvt_kernel<<<dim3(1024), dim3(256), 0, stream>>>(Wq, WT, 2048, 2048);
  trcvt_kernel<<<dim3(256),  dim3(256), 0, stream>>>(Wk, WT + (size_t)2048 * 2048, 2048, 512);
  trcvt_kernel<<<dim3(256),  dim3(256), 0, stream>>>(Wv, WT + (size_t)2560 * 2048, 2048, 512);
  trcvt_kernel<<<dim3(1024), dim3(256), 0, stream>>>(Wo, WoT, 2048, 2048);
  gates_kernel<<<dim3(512), dim3(256), 0, stream>>>(x, Wg, gg);

  // fused q|k|v projection + RoPE + layout epilogue
  gemm_qkv_kernel<<<dim3(16, 24), dim3(256), 0, stream>>>(xb, WT, ct, st, qB, kB, vbr, vB2);

  cgemm_kernel<<<dim3(512), dim3(256), 0, stream>>>(kB, vbr, Wck, Wcv, kc, vc);

  attn_kernel<<<dim3(32, 32), dim3(256), 0, stream>>>(qB, kB, vB2, kc, vc, gg, comb);

  gemm_bt_kernel<<<dim3(16, 16), dim3(256), 0, stream>>>(comb, WoT, out, 2048, 2048, 2048);
}